// Round 1
// baseline (551.409 us; speedup 1.0000x reference)
//
#include <hip/hip_runtime.h>

#define N_NODES 100000
#define N_EDGES 3200000
#define F_IN    128
#define DIM     16   // conv1 out == conv2 out == HID

// ---------------------------------------------------------------------------
// deg count: deg[col[e]] += 1 for each edge (self-loop +1 folded into rsqrt)
// ---------------------------------------------------------------------------
__global__ void count_deg(const int* __restrict__ col, float* __restrict__ deg, int E) {
    int e = blockIdx.x * blockDim.x + threadIdx.x;
    if (e < E) atomicAdd(&deg[col[e]], 1.0f);
}

__global__ void make_dinv(float* __restrict__ deg, int n) {
    int i = blockIdx.x * blockDim.x + threadIdx.x;
    if (i < n) deg[i] = rsqrtf(deg[i] + 1.0f);   // +1 = self-loop; always > 0
}

// ---------------------------------------------------------------------------
// GEMM1: h[N,16] = x[N,128] @ W[128,16].  16 rows per 256-thread block.
// ---------------------------------------------------------------------------
__global__ __launch_bounds__(256) void gemm1(const float* __restrict__ x,
                                             const float* __restrict__ W,
                                             float* __restrict__ h) {
    __shared__ float sW[F_IN * DIM];       // 8 KB
    __shared__ float sX[16][F_IN + 4];     // pad +4 floats: rows land in different banks
    const int t = threadIdx.x;
    for (int i = t; i < F_IN * DIM; i += 256) sW[i] = W[i];
    const int base = blockIdx.x * 16;      // N = 100000 = 6250 * 16, exact
    for (int i = t; i < 16 * F_IN; i += 256) {
        int r = i >> 7, k = i & (F_IN - 1);
        sX[r][k] = x[(size_t)(base + r) * F_IN + k];   // coalesced
    }
    __syncthreads();
    const int row = t >> 4, cj = t & 15;
    float acc = 0.f;
#pragma unroll
    for (int k = 0; k < F_IN; ++k) acc += sX[row][k] * sW[k * DIM + cj];
    h[(size_t)(base + row) * DIM + cj] = acc;
}

// ---------------------------------------------------------------------------
// GEMM2: h2[N,16] = h1[N,16] @ W[16,16]
// ---------------------------------------------------------------------------
__global__ __launch_bounds__(256) void gemm2(const float* __restrict__ xin,
                                             const float* __restrict__ W,
                                             float* __restrict__ h, int n) {
    __shared__ float sW[DIM * DIM];
    const int t = threadIdx.x;
    if (t < DIM * DIM) sW[t] = W[t];
    __syncthreads();
    const int gid = blockIdx.x * 256 + t;
    if (gid >= n * DIM) return;
    const int i = gid >> 4, j = gid & 15;
    float acc = 0.f;
#pragma unroll
    for (int k = 0; k < DIM; ++k) acc += xin[(size_t)i * DIM + k] * sW[k * DIM + j];
    h[gid] = acc;
}

// ---------------------------------------------------------------------------
// scatter: agg[col[e]][j] += h[row[e]][j] * dinv[row]*dinv[col]
// one thread per (edge, j) -> 16 consecutive threads share an edge
// ---------------------------------------------------------------------------
__global__ void scatter(const int* __restrict__ row, const int* __restrict__ col,
                        const float* __restrict__ dinv, const float* __restrict__ h,
                        float* __restrict__ agg, int E) {
    int gid = blockIdx.x * blockDim.x + threadIdx.x;
    if (gid >= E * DIM) return;
    const int e = gid >> 4;
    const int j = gid & 15;
    const int r = row[e], c = col[e];
    const float nrm = dinv[r] * dinv[c];
    atomicAdd(&agg[(size_t)c * DIM + j], h[(size_t)r * DIM + j] * nrm);
}

// ---------------------------------------------------------------------------
// finish: out = relu(agg + h*dinv^2 (self loop) + b)   (in place on agg)
// ---------------------------------------------------------------------------
__global__ void finish(const float* __restrict__ h, const float* __restrict__ dinv,
                       const float* __restrict__ b, float* __restrict__ agg, int n) {
    int gid = blockIdx.x * blockDim.x + threadIdx.x;
    if (gid >= n * DIM) return;
    const int i = gid >> 4, j = gid & 15;
    const float d = dinv[i];
    const float v = agg[gid] + h[gid] * d * d + b[j];
    agg[gid] = v > 0.f ? v : 0.f;
}

extern "C" void kernel_launch(void* const* d_in, const int* in_sizes, int n_in,
                              void* d_out, int out_size, void* d_ws, size_t ws_size,
                              hipStream_t stream) {
    const float* x   = (const float*)d_in[0];
    const int*   ei  = (const int*)d_in[1];        // [2, E] flat: row then col
    const float* W1  = (const float*)d_in[2];
    const float* b1  = (const float*)d_in[3];
    const float* W2  = (const float*)d_in[4];
    const float* b2  = (const float*)d_in[5];
    float*       out = (float*)d_out;

    const int* row = ei;
    const int* col = ei + N_EDGES;

    // workspace layout (256B aligned)
    char* ws = (char*)d_ws;
    float* dinv = (float*)ws;                                        // N floats
    size_t off1 = ((size_t)N_NODES * 4 + 255) & ~(size_t)255;
    float* h    = (float*)(ws + off1);                               // N*16 floats
    size_t off2 = off1 + (((size_t)N_NODES * DIM * 4 + 255) & ~(size_t)255);
    float* agg  = (float*)(ws + off2);                               // N*16 floats

    const int B = 256;

    // --- degree / dinv ---
    hipMemsetAsync(dinv, 0, (size_t)N_NODES * 4, stream);
    count_deg<<<(N_EDGES + B - 1) / B, B, 0, stream>>>(col, dinv, N_EDGES);
    make_dinv<<<(N_NODES + B - 1) / B, B, 0, stream>>>(dinv, N_NODES);

    // --- layer 1 ---
    gemm1<<<N_NODES / 16, B, 0, stream>>>(x, W1, h);
    hipMemsetAsync(agg, 0, (size_t)N_NODES * DIM * 4, stream);
    scatter<<<(N_EDGES * DIM + B - 1) / B, B, 0, stream>>>(row, col, dinv, h, agg, N_EDGES);
    finish<<<(N_NODES * DIM + B - 1) / B, B, 0, stream>>>(h, dinv, b1, agg, N_NODES);
    // agg now holds relu'd layer-1 output

    // --- layer 2 ---
    gemm2<<<(N_NODES * DIM + B - 1) / B, B, 0, stream>>>(agg, W2, h, N_NODES);
    hipMemsetAsync(out, 0, (size_t)N_NODES * DIM * 4, stream);
    scatter<<<(N_EDGES * DIM + B - 1) / B, B, 0, stream>>>(row, col, dinv, h, out, N_EDGES);
    finish<<<(N_NODES * DIM + B - 1) / B, B, 0, stream>>>(h, dinv, b2, out, N_NODES);
}

// Round 2
// 497.967 us; speedup vs baseline: 1.1073x; 1.1073x over previous
//
#include <hip/hip_runtime.h>

#define N_NODES 100000
#define N_EDGES 3200000
#define F_IN    128
#define DIM     16          // conv1 out == conv2 out
#define SCAN_E  1024        // elements per scan block
#define SCAN_NB ((N_NODES + SCAN_E - 1) / SCAN_E)   // 98

static inline size_t alignup(size_t x) { return (x + 255) & ~(size_t)255; }

// ---------------------------------------------------------------------------
// degree count (int atomics into 400KB L2-resident array)
// ---------------------------------------------------------------------------
__global__ void count_deg_i(const int* __restrict__ col, int* __restrict__ cnt, int E) {
    int e = blockIdx.x * blockDim.x + threadIdx.x;
    if (e < E) atomicAdd(&cnt[col[e]], 1);
}

__global__ void make_dinv(const int* __restrict__ cnt, float* __restrict__ dinv, int n) {
    int i = blockIdx.x * blockDim.x + threadIdx.x;
    if (i < n) dinv[i] = rsqrtf((float)cnt[i] + 1.0f);   // +1 = self-loop
}

// ---------------------------------------------------------------------------
// 3-kernel exclusive scan of cnt[N] -> rowptr[N] (+ rowptr[N]=E, cursor init)
// ---------------------------------------------------------------------------
__global__ __launch_bounds__(256) void scan1(const int* __restrict__ cnt,
                                             int* __restrict__ rowptr,
                                             int* __restrict__ bsum, int n) {
    __shared__ int lds[256];
    const int b = blockIdx.x, t = threadIdx.x;
    const int base = b * SCAN_E + t * 4;
    int v0 = 0, v1 = 0, v2 = 0, v3 = 0;
    if (base + 3 < n) {
        int4 q = *(const int4*)(cnt + base);
        v0 = q.x; v1 = q.y; v2 = q.z; v3 = q.w;
    } else {
        if (base + 0 < n) v0 = cnt[base + 0];
        if (base + 1 < n) v1 = cnt[base + 1];
        if (base + 2 < n) v2 = cnt[base + 2];
    }
    const int tot = v0 + v1 + v2 + v3;
    lds[t] = tot;
    __syncthreads();
#pragma unroll
    for (int off = 1; off < 256; off <<= 1) {
        int add = (t >= off) ? lds[t - off] : 0;
        __syncthreads();
        lds[t] += add;
        __syncthreads();
    }
    const int excl = lds[t] - tot;              // block-local exclusive prefix
    if (base + 0 < n) rowptr[base + 0] = excl;
    if (base + 1 < n) rowptr[base + 1] = excl + v0;
    if (base + 2 < n) rowptr[base + 2] = excl + v0 + v1;
    if (base + 3 < n) rowptr[base + 3] = excl + v0 + v1 + v2;
    if (t == 255) bsum[b] = lds[255];           // block total
}

__global__ void scan2(int* __restrict__ bsum, int nb) {
    __shared__ int lds[256];
    const int t = threadIdx.x;
    const int v = (t < nb) ? bsum[t] : 0;
    lds[t] = v;
    __syncthreads();
#pragma unroll
    for (int off = 1; off < 256; off <<= 1) {
        int add = (t >= off) ? lds[t - off] : 0;
        __syncthreads();
        lds[t] += add;
        __syncthreads();
    }
    if (t < nb) bsum[t] = lds[t] - v;           // exclusive
}

__global__ __launch_bounds__(256) void scan3(int* __restrict__ rowptr,
                                             int* __restrict__ cursor,
                                             const int* __restrict__ bsum,
                                             int n, int total) {
    const int b = blockIdx.x, t = threadIdx.x;
    const int add = bsum[b];
    const int base = b * SCAN_E + t * 4;
#pragma unroll
    for (int q = 0; q < 4; ++q) {
        int i = base + q;
        if (i < n) { int r = rowptr[i] + add; rowptr[i] = r; cursor[i] = r; }
    }
    if (b == 0 && t == 0) rowptr[n] = total;
}

// ---------------------------------------------------------------------------
// CSR fill: edges grouped by destination; per-edge norm precomputed
// ---------------------------------------------------------------------------
__global__ void fill_csr(const int* __restrict__ row, const int* __restrict__ col,
                         const float* __restrict__ dinv, int* __restrict__ cursor,
                         int2* __restrict__ edges, int E) {
    int e = blockIdx.x * blockDim.x + threadIdx.x;
    if (e >= E) return;
    const int r = row[e], c = col[e];
    const int pos = atomicAdd(&cursor[c], 1);
    const float nrm = dinv[r] * dinv[c];
    edges[pos] = make_int2(r, __float_as_int(nrm));
}

// ---------------------------------------------------------------------------
// GEMM1: h[N,16] = x[N,128] @ W1[128,16]; 16 rows per 256-thread block
// ---------------------------------------------------------------------------
__global__ __launch_bounds__(256) void gemm1(const float* __restrict__ x,
                                             const float* __restrict__ W,
                                             float* __restrict__ h) {
    __shared__ float4 sW4[F_IN * DIM / 4];       // 8 KB
    __shared__ float4 sX4[16][F_IN / 4 + 1];     // +1 float4 pad per row
    const int t = threadIdx.x;
#pragma unroll
    for (int i = t; i < F_IN * DIM / 4; i += 256) sW4[i] = ((const float4*)W)[i];
    const int base = blockIdx.x * 16;            // N % 16 == 0
#pragma unroll
    for (int i = t; i < 16 * (F_IN / 4); i += 256) {
        int r = i >> 5, k4 = i & 31;
        sX4[r][k4] = ((const float4*)(x + (size_t)(base + r) * F_IN))[k4];
    }
    __syncthreads();
    const float* sW = (const float*)sW4;
    const int rrow = t >> 4, cj = t & 15;
    const float* xr = (const float*)&sX4[rrow][0];
    float acc = 0.f;
#pragma unroll
    for (int k = 0; k < F_IN; ++k) acc += xr[k] * sW[k * DIM + cj];
    h[(size_t)(base + rrow) * DIM + cj] = acc;
}

// ---------------------------------------------------------------------------
// Layer-1 aggregate (gather, no atomics) + bias + ReLU, fused with GEMM2.
// 16 lanes per destination node; lane j owns feature j.
// ---------------------------------------------------------------------------
__global__ __launch_bounds__(256) void agg1_gemm2(const int2* __restrict__ edges,
                                                  const int* __restrict__ rowptr,
                                                  const float* __restrict__ dinv,
                                                  const float* __restrict__ h,
                                                  const float* __restrict__ b1,
                                                  const float* __restrict__ W2,
                                                  float* __restrict__ h2, int n) {
    __shared__ float sW2[DIM * DIM];
    __shared__ float sB[16][DIM + 1];            // +1 pad
    const int t = threadIdx.x;
    if (t < DIM * DIM) sW2[t] = W2[t];
    const int gid = blockIdx.x * 256 + t;
    const int c = gid >> 4, j = gid & 15, nl = t >> 4;
    float val = 0.f;
    if (c < n) {
        const int start = rowptr[c], end = rowptr[c + 1];
        const float d = dinv[c];
        float acc = h[(size_t)c * DIM + j] * d * d;       // self loop
        for (int p = start; p < end; ++p) {
            int2 v = edges[p];
            acc += __int_as_float(v.y) * h[(size_t)v.x * DIM + j];
        }
        acc += b1[j];
        val = acc > 0.f ? acc : 0.f;                       // relu(layer1)
    }
    sB[nl][j] = val;
    __syncthreads();
    if (c >= n) return;
    float acc2 = 0.f;
#pragma unroll
    for (int k = 0; k < DIM; ++k) acc2 += sB[nl][k] * sW2[k * DIM + j];
    h2[(size_t)c * DIM + j] = acc2;                        // relu(l1) @ W2
}

// ---------------------------------------------------------------------------
// Layer-2 aggregate + bias + ReLU -> out
// ---------------------------------------------------------------------------
__global__ __launch_bounds__(256) void agg2(const int2* __restrict__ edges,
                                            const int* __restrict__ rowptr,
                                            const float* __restrict__ dinv,
                                            const float* __restrict__ h2,
                                            const float* __restrict__ b2,
                                            float* __restrict__ out, int n) {
    const int gid = blockIdx.x * 256 + threadIdx.x;
    const int c = gid >> 4, j = gid & 15;
    if (c >= n) return;
    const int start = rowptr[c], end = rowptr[c + 1];
    const float d = dinv[c];
    float acc = h2[(size_t)c * DIM + j] * d * d;
    for (int p = start; p < end; ++p) {
        int2 v = edges[p];
        acc += __int_as_float(v.y) * h2[(size_t)v.x * DIM + j];
    }
    acc += b2[j];
    out[(size_t)c * DIM + j] = acc > 0.f ? acc : 0.f;
}

// ---------------------------------------------------------------------------
// Fallback path (round-0 atomic scatter) if ws_size is too small for CSR
// ---------------------------------------------------------------------------
__global__ void count_deg_f(const int* __restrict__ col, float* __restrict__ deg, int E) {
    int e = blockIdx.x * blockDim.x + threadIdx.x;
    if (e < E) atomicAdd(&deg[col[e]], 1.0f);
}
__global__ void make_dinv_f(float* __restrict__ deg, int n) {
    int i = blockIdx.x * blockDim.x + threadIdx.x;
    if (i < n) deg[i] = rsqrtf(deg[i] + 1.0f);
}
__global__ __launch_bounds__(256) void gemm2_plain(const float* __restrict__ xin,
                                                   const float* __restrict__ W,
                                                   float* __restrict__ h, int n) {
    __shared__ float sW[DIM * DIM];
    const int t = threadIdx.x;
    if (t < DIM * DIM) sW[t] = W[t];
    __syncthreads();
    const int gid = blockIdx.x * 256 + t;
    if (gid >= n * DIM) return;
    const int i = gid >> 4, j = gid & 15;
    float acc = 0.f;
#pragma unroll
    for (int k = 0; k < DIM; ++k) acc += xin[(size_t)i * DIM + k] * sW[k * DIM + j];
    h[gid] = acc;
}
__global__ void scatter(const int* __restrict__ row, const int* __restrict__ col,
                        const float* __restrict__ dinv, const float* __restrict__ h,
                        float* __restrict__ agg, int E) {
    int gid = blockIdx.x * blockDim.x + threadIdx.x;
    if (gid >= E * DIM) return;
    const int e = gid >> 4, j = gid & 15;
    const int r = row[e], c = col[e];
    const float nrm = dinv[r] * dinv[c];
    atomicAdd(&agg[(size_t)c * DIM + j], h[(size_t)r * DIM + j] * nrm);
}
__global__ void finish(const float* __restrict__ h, const float* __restrict__ dinv,
                       const float* __restrict__ b, float* __restrict__ agg, int n) {
    int gid = blockIdx.x * blockDim.x + threadIdx.x;
    if (gid >= n * DIM) return;
    const int i = gid >> 4, j = gid & 15;
    const float d = dinv[i];
    const float v = agg[gid] + h[gid] * d * d + b[j];
    agg[gid] = v > 0.f ? v : 0.f;
}

extern "C" void kernel_launch(void* const* d_in, const int* in_sizes, int n_in,
                              void* d_out, int out_size, void* d_ws, size_t ws_size,
                              hipStream_t stream) {
    const float* x   = (const float*)d_in[0];
    const int*   ei  = (const int*)d_in[1];        // [2, E] flat: row then col
    const float* W1  = (const float*)d_in[2];
    const float* b1  = (const float*)d_in[3];
    const float* W2  = (const float*)d_in[4];
    const float* b2  = (const float*)d_in[5];
    float*       out = (float*)d_out;

    const int* row = ei;
    const int* col = ei + N_EDGES;
    const int  B   = 256;

    // ---- fast-path workspace layout ----
    char* ws = (char*)d_ws;
    size_t o = 0;
    auto take = [&](size_t bytes) { char* p = ws + o; o = alignup(o + bytes); return p; };
    int*   cnt    = (int*)  take((size_t)N_NODES * 4);
    float* dinv   = (float*)take((size_t)N_NODES * 4);
    int*   rowptr = (int*)  take((size_t)(N_NODES + 1) * 4);
    int*   cursor = (int*)  take((size_t)N_NODES * 4);
    int*   bsum   = (int*)  take((size_t)SCAN_NB * 4);
    int2*  edges  = (int2*) take((size_t)N_EDGES * 8);
    float* h      = (float*)take((size_t)N_NODES * DIM * 4);
    float* h2     = (float*)take((size_t)N_NODES * DIM * 4);
    const size_t need = o;

    if (need <= ws_size) {
        // ---------- CSR gather path ----------
        hipMemsetAsync(cnt, 0, (size_t)N_NODES * 4, stream);
        count_deg_i<<<(N_EDGES + B - 1) / B, B, 0, stream>>>(col, cnt, N_EDGES);
        make_dinv<<<(N_NODES + B - 1) / B, B, 0, stream>>>(cnt, dinv, N_NODES);
        scan1<<<SCAN_NB, B, 0, stream>>>(cnt, rowptr, bsum, N_NODES);
        scan2<<<1, B, 0, stream>>>(bsum, SCAN_NB);
        scan3<<<SCAN_NB, B, 0, stream>>>(rowptr, cursor, bsum, N_NODES, N_EDGES);
        fill_csr<<<(N_EDGES + B - 1) / B, B, 0, stream>>>(row, col, dinv, cursor, edges, N_EDGES);
        gemm1<<<N_NODES / 16, B, 0, stream>>>(x, W1, h);
        agg1_gemm2<<<(N_NODES * DIM + B - 1) / B, B, 0, stream>>>(edges, rowptr, dinv, h,
                                                                  b1, W2, h2, N_NODES);
        agg2<<<(N_NODES * DIM + B - 1) / B, B, 0, stream>>>(edges, rowptr, dinv, h2,
                                                            b2, out, N_NODES);
    } else {
        // ---------- fallback: round-0 atomic scatter path ----------
        size_t oo = 0;
        auto takeo = [&](size_t bytes) { char* p = ws + oo; oo = alignup(oo + bytes); return p; };
        float* fdinv = (float*)takeo((size_t)N_NODES * 4);
        float* fh    = (float*)takeo((size_t)N_NODES * DIM * 4);
        float* fagg  = (float*)takeo((size_t)N_NODES * DIM * 4);

        hipMemsetAsync(fdinv, 0, (size_t)N_NODES * 4, stream);
        count_deg_f<<<(N_EDGES + B - 1) / B, B, 0, stream>>>(col, fdinv, N_EDGES);
        make_dinv_f<<<(N_NODES + B - 1) / B, B, 0, stream>>>(fdinv, N_NODES);

        gemm1<<<N_NODES / 16, B, 0, stream>>>(x, W1, fh);
        hipMemsetAsync(fagg, 0, (size_t)N_NODES * DIM * 4, stream);
        scatter<<<((size_t)N_EDGES * DIM + B - 1) / B, B, 0, stream>>>(row, col, fdinv, fh, fagg, N_EDGES);
        finish<<<(N_NODES * DIM + B - 1) / B, B, 0, stream>>>(fh, fdinv, b1, fagg, N_NODES);

        gemm2_plain<<<(N_NODES * DIM + B - 1) / B, B, 0, stream>>>(fagg, W2, fh, N_NODES);
        hipMemsetAsync(out, 0, (size_t)N_NODES * DIM * 4, stream);
        scatter<<<((size_t)N_EDGES * DIM + B - 1) / B, B, 0, stream>>>(row, col, fdinv, fh, out, N_EDGES);
        finish<<<(N_NODES * DIM + B - 1) / B, B, 0, stream>>>(fh, fdinv, b2, out, N_NODES);
    }
}